// Round 8
// baseline (160.658 us; speedup 1.0000x reference)
//
#include <hip/hip_runtime.h>
#include <hip/hip_bf16.h>

typedef __attribute__((ext_vector_type(8))) short bf16x8;
typedef __attribute__((ext_vector_type(4))) float f32x4;

#define D128 128
#define IMG_SHORTS 16384          // one W frag-image: 32 frags x 64 lanes x 8 bf16 = 32 KB
#define XB_OFF 65536              // xb at 128 KiB into d_ws (in shorts)
#define NBLK 256
#define TROWS 256                 // rows per tile (16 waves x 16 rows)

__device__ __forceinline__ short f2bf(float f) {
    union { float f; unsigned u; } v; v.f = f;
    unsigned r = (v.u + 0x7FFFu + ((v.u >> 16) & 1u)) >> 16;  // RNE
    return (short)r;
}

__device__ __forceinline__ short f2bf_h(float f) {
    __hip_bfloat16 h = __float2bfloat16(f);
    short s;
    __builtin_memcpy(&s, &h, sizeof(short));
    return s;
}

__device__ __forceinline__ bf16x8 pack8(float4 a, float4 b) {
    bf16x8 r;
    r[0] = f2bf_h(a.x); r[1] = f2bf_h(a.y); r[2] = f2bf_h(a.z); r[3] = f2bf_h(a.w);
    r[4] = f2bf_h(b.x); r[5] = f2bf_h(b.y); r[6] = f2bf_h(b.z); r[7] = f2bf_h(b.w);
    return r;
}

__device__ __forceinline__ void gload_lds16(const short* g, short* l) {
    __builtin_amdgcn_global_load_lds(
        (const __attribute__((address_space(1))) unsigned int*)(const void*)g,
        (__attribute__((address_space(3))) unsigned int*)(void*)l, 16, 0, 0);
}

// W (3*128 x 128 fp32 row-major) -> 3 A-operand fragment images (src,dst,e):
// img[c][frag=mt*4+ks][lane][j] = W[c*128 + ks*32 + (lane>>4)*8 + j][mt*16 + (lane&15)]
__global__ __launch_bounds__(256) void wt_kernel(const float* __restrict__ W,
                                                 short* __restrict__ Wimg) {
    const int c    = blockIdx.x >> 3;
    const int frag = (blockIdx.x & 7) * 4 + (threadIdx.x >> 6);
    const int lane = threadIdx.x & 63;
    const int mt = frag >> 2, ks = frag & 3;
    const int m  = mt * 16 + (lane & 15);
    const int k0 = ks * 32 + (lane >> 4) * 8;
    bf16x8 v;
#pragma unroll
    for (int j = 0; j < 8; ++j)
        v[j] = f2bf(W[(size_t)(c * 128 + k0 + j) * D128 + m]);
    *reinterpret_cast<bf16x8*>(
        &Wimg[((size_t)c * 32 + frag) * 64 * 8 + (size_t)lane * 8]) = v;
}

// x (fp32) -> xb (bf16), 8 elems/thread.
__global__ __launch_bounds__(256) void xb_kernel(const float* __restrict__ x,
                                                 short* __restrict__ xb) {
    const size_t i = ((size_t)blockIdx.x * 256 + threadIdx.x) * 8;
    float4 v0 = reinterpret_cast<const float4*>(x + i)[0];
    float4 v1 = reinterpret_cast<const float4*>(x + i)[1];
    *reinterpret_cast<bf16x8*>(xb + i) = pack8(v0, v1);
}

// Persistent-W fused gather-GEMM:
// out[r] = [x[src[r]] | x[dst[r]] | e[r]] @ W   (bf16 MFMA, fp32 acc)
// 256 blocks x 1024 thr. Each block stages all 3 W images once (96 KB LDS,
// ONE barrier), then loops over a contiguous range of 256-row tiles with no
// barriers / no LDS writes. Lane owns output row rn = t*256 + w*16+(lane&15).
__global__ __launch_bounds__(1024, 4) void fused_kernel(
        const short* __restrict__ xb,
        const float* __restrict__ e,
        const short* __restrict__ Wimg,
        const int*  __restrict__ src_idx,
        const int*  __restrict__ dst_idx,
        float* __restrict__ out,
        int E, int ntiles)
{
    __shared__ short Ws[3 * IMG_SHORTS];   // 96 KB

    const int tid  = threadIdx.x;
    const int lane = tid & 63;
    const int w    = tid >> 6;            // 0..15
    const int lhi  = lane >> 4;           // 0..3
    const int roff = w * 16 + (lane & 15);

    // contiguous tile range for this block
    const int per = ntiles >> 8;          // ntiles / 256
    const int rem = ntiles & 255;
    const int b   = blockIdx.x;
    const int t0  = b * per + (b < rem ? b : rem);
    const int t1  = t0 + per + (b < rem ? 1 : 0);

    // ---- stage all 3 W images: 6144 x 16B units, 6 per thread, linear ----
#pragma unroll
    for (int jj = 0; jj < 6; ++jj) {
        int unit = jj * 1024 + tid;
        gload_lds16(Wimg + (size_t)unit * 8, &Ws[unit * 8]);
    }
    asm volatile("" ::: "memory");

    // ---- prologue: first tile's idx (kept flying past the stage drain) ----
    int rp = t0 * TROWS + roff; if (rp >= E) rp = E - 1;
    int si = src_idx[rp];
    int di = dst_idx[rp];
    asm volatile("" ::: "memory");
    asm volatile("s_waitcnt vmcnt(2)" ::: "memory");   // 6 stage DMAs drained
    __builtin_amdgcn_s_barrier();                      // the ONLY barrier

    for (int t = t0; t < t1; ++t) {
        const int rn = t * TROWS + roff;
        const bool valid = rn < E;
        const int  rl = valid ? rn : (E - 1);

        // ---- issue gathers (uses si/di; compiler inserts the idx wait) ----
        const short* ps = xb + (size_t)si * D128;
        const short* pd = xb + (size_t)di * D128;
        bf16x8 bs[4], bd[4];
#pragma unroll
        for (int ks = 0; ks < 4; ++ks) {
            bs[ks] = *reinterpret_cast<const bf16x8*>(ps + ks * 32 + lhi * 8);
            bd[ks] = *reinterpret_cast<const bf16x8*>(pd + ks * 32 + lhi * 8);
        }
        // ---- issue e row loads ----
        const float* pe = e + (size_t)rl * D128;
        float4 ev[8];
#pragma unroll
        for (int ks = 0; ks < 4; ++ks) {
            ev[2 * ks]     = reinterpret_cast<const float4*>(pe + ks * 32 + lhi * 8)[0];
            ev[2 * ks + 1] = reinterpret_cast<const float4*>(pe + ks * 32 + lhi * 8)[1];
        }
        // ---- prefetch next tile's idx ----
        int rpn = (t + 1) * TROWS + roff; if (rpn >= E) rpn = E - 1;
        si = src_idx[rpn];
        di = dst_idx[rpn];
        asm volatile("" ::: "memory");   // pin: all loads issued before compute

        f32x4 acc[8];
#pragma unroll
        for (int mt = 0; mt < 8; ++mt) acc[mt] = (f32x4){0.f, 0.f, 0.f, 0.f};

        // ---- chunk 0: src ----
#pragma unroll
        for (int ks = 0; ks < 4; ++ks)
#pragma unroll
            for (int mt = 0; mt < 8; ++mt) {
                bf16x8 a = *reinterpret_cast<const bf16x8*>(
                    &Ws[((0 * 32 + mt * 4 + ks) * 64 + lane) * 8]);
                acc[mt] = __builtin_amdgcn_mfma_f32_16x16x32_bf16(a, bs[ks], acc[mt], 0, 0, 0);
            }
        // ---- chunk 1: dst ----
#pragma unroll
        for (int ks = 0; ks < 4; ++ks)
#pragma unroll
            for (int mt = 0; mt < 8; ++mt) {
                bf16x8 a = *reinterpret_cast<const bf16x8*>(
                    &Ws[((1 * 32 + mt * 4 + ks) * 64 + lane) * 8]);
                acc[mt] = __builtin_amdgcn_mfma_f32_16x16x32_bf16(a, bd[ks], acc[mt], 0, 0, 0);
            }
        // ---- chunk 2: e (convert then MFMA) ----
        bf16x8 be[4];
#pragma unroll
        for (int ks = 0; ks < 4; ++ks) be[ks] = pack8(ev[2 * ks], ev[2 * ks + 1]);
#pragma unroll
        for (int ks = 0; ks < 4; ++ks)
#pragma unroll
            for (int mt = 0; mt < 8; ++mt) {
                bf16x8 a = *reinterpret_cast<const bf16x8*>(
                    &Ws[((2 * 32 + mt * 4 + ks) * 64 + lane) * 8]);
                acc[mt] = __builtin_amdgcn_mfma_f32_16x16x32_bf16(a, be[ks], acc[mt], 0, 0, 0);
            }

        // ---- epilogue: lane holds out[rn][mt*16 + lhi*4 .. +3] ----
        if (valid) {
            float* po = out + (size_t)rn * D128 + lhi * 4;
#pragma unroll
            for (int mt = 0; mt < 8; ++mt)
                *reinterpret_cast<float4*>(po + mt * 16) = *(float4*)&acc[mt];
        }
    }
}

extern "C" void kernel_launch(void* const* d_in, const int* in_sizes, int n_in,
                              void* d_out, int out_size, void* d_ws, size_t ws_size,
                              hipStream_t stream) {
    const float* x = (const float*)d_in[0];
    const float* e = (const float*)d_in[1];
    const float* W = (const float*)d_in[2];
    const int* src = (const int*)d_in[3];
    const int* dst = (const int*)d_in[4];
    float* out = (float*)d_out;

    short* Wimg = (short*)d_ws;                 // 3 x 32 KB frag images
    short* xb   = (short*)d_ws + XB_OFF;        // 100000*128 bf16 = 25.6 MB

    const int N = in_sizes[0] / D128;           // 100000
    const int E = in_sizes[3];                  // 400000
    const int ntiles = (E + TROWS - 1) / TROWS; // 1563

    wt_kernel<<<24, 256, 0, stream>>>(W, Wimg);
    xb_kernel<<<(N * D128) / (256 * 8), 256, 0, stream>>>(x, xb);
    fused_kernel<<<NBLK, 1024, 0, stream>>>(xb, e, Wimg, src, dst, out, E, ntiles);
}

// Round 9
// 148.810 us; speedup vs baseline: 1.0796x; 1.0796x over previous
//
#include <hip/hip_runtime.h>
#include <hip/hip_bf16.h>

typedef __attribute__((ext_vector_type(8))) short bf16x8;
typedef __attribute__((ext_vector_type(4))) float f32x4;

#define D128 128
#define IMG_SHORTS 16384          // one W frag-image: 32 frags x 64 lanes x 8 bf16 = 32 KB
#define XB_OFF 65536              // xb at 128 KiB into d_ws (in shorts)
#define NBLK 256
#define WSH (3 * IMG_SHORTS)      // 49152 shorts = 96 KB of W images
#define RBS 4096                  // row-buffer shorts per wave (8 KB: src 4K + dst 4K)

__device__ __forceinline__ short f2bf(float f) {
    union { float f; unsigned u; } v; v.f = f;
    unsigned r = (v.u + 0x7FFFu + ((v.u >> 16) & 1u)) >> 16;  // RNE
    return (short)r;
}

__device__ __forceinline__ short f2bf_h(float f) {
    __hip_bfloat16 h = __float2bfloat16(f);
    short s;
    __builtin_memcpy(&s, &h, sizeof(short));
    return s;
}

__device__ __forceinline__ bf16x8 pack8(float4 a, float4 b) {
    bf16x8 r;
    r[0] = f2bf_h(a.x); r[1] = f2bf_h(a.y); r[2] = f2bf_h(a.z); r[3] = f2bf_h(a.w);
    r[4] = f2bf_h(b.x); r[5] = f2bf_h(b.y); r[6] = f2bf_h(b.z); r[7] = f2bf_h(b.w);
    return r;
}

__device__ __forceinline__ void gload_lds16(const short* g, short* l) {
    __builtin_amdgcn_global_load_lds(
        (const __attribute__((address_space(1))) unsigned int*)(const void*)g,
        (__attribute__((address_space(3))) unsigned int*)(void*)l, 16, 0, 0);
}

// W (3*128 x 128 fp32 row-major) -> 3 A-operand fragment images (src,dst,e):
// img[c][frag=mt*4+ks][lane][j] = W[c*128 + ks*32 + (lane>>4)*8 + j][mt*16 + (lane&15)]
__global__ __launch_bounds__(256) void wt_kernel(const float* __restrict__ W,
                                                 short* __restrict__ Wimg) {
    const int c    = blockIdx.x >> 3;
    const int frag = (blockIdx.x & 7) * 4 + (threadIdx.x >> 6);
    const int lane = threadIdx.x & 63;
    const int mt = frag >> 2, ks = frag & 3;
    const int m  = mt * 16 + (lane & 15);
    const int k0 = ks * 32 + (lane >> 4) * 8;
    bf16x8 v;
#pragma unroll
    for (int j = 0; j < 8; ++j)
        v[j] = f2bf(W[(size_t)(c * 128 + k0 + j) * D128 + m]);
    *reinterpret_cast<bf16x8*>(
        &Wimg[((size_t)c * 32 + frag) * 64 * 8 + (size_t)lane * 8]) = v;
}

// x (fp32) -> xb (bf16), 8 elems/thread.
__global__ __launch_bounds__(256) void xb_kernel(const float* __restrict__ x,
                                                 short* __restrict__ xb) {
    const size_t i = ((size_t)blockIdx.x * 256 + threadIdx.x) * 8;
    float4 v0 = reinterpret_cast<const float4*>(x + i)[0];
    float4 v1 = reinterpret_cast<const float4*>(x + i)[1];
    *reinterpret_cast<bf16x8*>(xb + i) = pack8(v0, v1);
}

// DMA-gather fused kernel. 512 thr = 8 waves, wave owns 16 rows/tile, tile=128 rows.
// LDS: [0,96K) = 3 W frag-images (staged once); + 8 KB private buf per wave
// (src frags [0,4K), dst frags [4K,8K)). Gathers go global->LDS via
// global_load_lds (per-lane source addr, zero VGPR cost), prefetched across
// iterations; e rows stream through VGPRs. No barriers in the loop; counted
// vmcnt chain 14 -> 10 -> 6 per iteration (never drains the prefetch).
__global__ __launch_bounds__(512, 2) void fused_kernel(
        const short* __restrict__ xb,
        const float* __restrict__ e,
        const short* __restrict__ Wimg,
        const int*  __restrict__ src_idx,
        const int*  __restrict__ dst_idx,
        float* __restrict__ out,
        int E, int ntiles)
{
    __shared__ short lds[WSH + 8 * RBS];   // 160 KB exact

    const int tid  = threadIdx.x;
    const int lane = tid & 63;
    const int w    = tid >> 6;            // 0..7
    const int lhi  = lane >> 4;           // 0..3 (k-quarter owner)
    const int l15  = lane & 15;           // row owner within wave
    short* RB = &lds[WSH + w * RBS];

    // contiguous tile range for this block
    const int per = ntiles >> 8;
    const int rem = ntiles & 255;
    const int b   = blockIdx.x;
    const int t0  = b * per + (b < rem ? b : rem);
    const int t1  = t0 + per + (b < rem ? 1 : 0);

    // ---- prologue: stage W images (12 DMA/thread, linear both sides) ----
#pragma unroll
    for (int jj = 0; jj < 12; ++jj) {
        int unit = jj * 512 + tid;
        gload_lds16(Wimg + (size_t)unit * 8, &lds[unit * 8]);
    }
    // idx for t0
    int rp = t0 * 128 + w * 16 + l15;
    int si = src_idx[rp];
    int di = dst_idx[rp];
    asm volatile("" ::: "memory");
    asm volatile("s_waitcnt vmcnt(0)" ::: "memory");
    __builtin_amdgcn_s_barrier();          // the only barrier

    // ---- DMA src[t0] frags: lane supplies (row l15, quarter lhi) source ----
#pragma unroll
    for (int ks = 0; ks < 4; ++ks)
        gload_lds16(xb + (size_t)si * D128 + ks * 32 + lhi * 8, &RB[ks * 512]);
    asm volatile("" ::: "memory");

    for (int t = t0; t < t1; ++t) {
        const int rn = t * 128 + w * 16 + l15;

        // ---- issue DMA dst[t] (4) ----
#pragma unroll
        for (int ks = 0; ks < 4; ++ks)
            gload_lds16(xb + (size_t)di * D128 + ks * 32 + lhi * 8,
                        &RB[2048 + ks * 512]);
        asm volatile("" ::: "memory");

        // ---- issue e row loads (8) ----
        const float* pe = e + (size_t)rn * D128;
        float4 ev[8];
#pragma unroll
        for (int ks = 0; ks < 4; ++ks) {
            ev[2 * ks]     = reinterpret_cast<const float4*>(pe + ks * 32 + lhi * 8)[0];
            ev[2 * ks + 1] = reinterpret_cast<const float4*>(pe + ks * 32 + lhi * 8)[1];
        }
        asm volatile("" ::: "memory");

        // ---- issue idx[t+1] (2) ----
        int rpn = (t + 1) * 128 + w * 16 + l15;
        if (rpn >= E) rpn = E - 1;
        const int sin_ = src_idx[rpn];
        const int din_ = dst_idx[rpn];
        asm volatile("" ::: "memory");

        // src[t] ready (retires idx_old+src4+stores; dst4+e8+idx2 keep flying)
        asm volatile("s_waitcnt vmcnt(14)" ::: "memory");
        __builtin_amdgcn_sched_barrier(0);

        f32x4 acc[8];
#pragma unroll
        for (int mt = 0; mt < 8; ++mt) acc[mt] = (f32x4){0.f, 0.f, 0.f, 0.f};

        // ---- chunk 0: src rows from RB[0,4K) ----
#pragma unroll
        for (int ks = 0; ks < 4; ++ks) {
            bf16x8 bfr = *reinterpret_cast<const bf16x8*>(&RB[ks * 512 + lane * 8]);
#pragma unroll
            for (int mt = 0; mt < 8; ++mt) {
                bf16x8 a = *reinterpret_cast<const bf16x8*>(
                    &lds[((0 * 32 + mt * 4 + ks) * 64 + lane) * 8]);
                acc[mt] = __builtin_amdgcn_mfma_f32_16x16x32_bf16(a, bfr, acc[mt], 0, 0, 0);
            }
        }

        // dst[t] ready (e8+idx2 keep flying)
        asm volatile("s_waitcnt vmcnt(10)" ::: "memory");
        __builtin_amdgcn_sched_barrier(0);

        // ---- chunk 1: dst rows from RB[4K,8K) ----
#pragma unroll
        for (int ks = 0; ks < 4; ++ks) {
            bf16x8 bfr = *reinterpret_cast<const bf16x8*>(&RB[2048 + ks * 512 + lane * 8]);
#pragma unroll
            for (int mt = 0; mt < 8; ++mt) {
                bf16x8 a = *reinterpret_cast<const bf16x8*>(
                    &lds[((1 * 32 + mt * 4 + ks) * 64 + lane) * 8]);
                acc[mt] = __builtin_amdgcn_mfma_f32_16x16x32_bf16(a, bfr, acc[mt], 0, 0, 0);
            }
        }
        asm volatile("" ::: "memory");

        // ---- issue DMA src[t+1] (4) into RB[0,4K) (chunk-0 reads long done) ----
#pragma unroll
        for (int ks = 0; ks < 4; ++ks)
            gload_lds16(xb + (size_t)sin_ * D128 + ks * 32 + lhi * 8, &RB[ks * 512]);
        asm volatile("" ::: "memory");
        si = sin_; di = din_;

        // e ready (idx2 + src'4 keep flying)
        asm volatile("s_waitcnt vmcnt(6)" ::: "memory");

        // ---- chunk 2: e (pack then MFMA) ----
        bf16x8 be[4];
#pragma unroll
        for (int ks = 0; ks < 4; ++ks) be[ks] = pack8(ev[2 * ks], ev[2 * ks + 1]);
#pragma unroll
        for (int ks = 0; ks < 4; ++ks)
#pragma unroll
            for (int mt = 0; mt < 8; ++mt) {
                bf16x8 a = *reinterpret_cast<const bf16x8*>(
                    &lds[((2 * 32 + mt * 4 + ks) * 64 + lane) * 8]);
                acc[mt] = __builtin_amdgcn_mfma_f32_16x16x32_bf16(a, be[ks], acc[mt], 0, 0, 0);
            }

        // ---- epilogue: lane owns out[rn][mt*16 + lhi*4 .. +3] ----
        float* po = out + (size_t)rn * D128 + lhi * 4;
#pragma unroll
        for (int mt = 0; mt < 8; ++mt)
            *reinterpret_cast<float4*>(po + mt * 16) = *(float4*)&acc[mt];
        asm volatile("" ::: "memory");   // stores precede next iter's issues
    }
}

extern "C" void kernel_launch(void* const* d_in, const int* in_sizes, int n_in,
                              void* d_out, int out_size, void* d_ws, size_t ws_size,
                              hipStream_t stream) {
    const float* x = (const float*)d_in[0];
    const float* e = (const float*)d_in[1];
    const float* W = (const float*)d_in[2];
    const int* src = (const int*)d_in[3];
    const int* dst = (const int*)d_in[4];
    float* out = (float*)d_out;

    short* Wimg = (short*)d_ws;                 // 3 x 32 KB frag images
    short* xb   = (short*)d_ws + XB_OFF;        // 100000*128 bf16 = 25.6 MB

    const int N = in_sizes[0] / D128;           // 100000
    const int E = in_sizes[3];                  // 400000
    const int ntiles = E / 128;                 // 3125 (exact)

    wt_kernel<<<24, 256, 0, stream>>>(W, Wimg);
    xb_kernel<<<(N * D128) / (256 * 8), 256, 0, stream>>>(x, xb);
    fused_kernel<<<NBLK, 512, 0, stream>>>(xb, e, Wimg, src, dst, out, E, ntiles);
}

// Round 11
// 129.492 us; speedup vs baseline: 1.2407x; 1.1492x over previous
//
#include <hip/hip_runtime.h>
#include <hip/hip_bf16.h>

typedef __attribute__((ext_vector_type(8))) short bf16x8;
typedef __attribute__((ext_vector_type(4))) float f32x4;

#define D128 128
#define IMG_SHORTS 16384          // one W frag-image: 32 frags x 64 lanes x 8 bf16 = 32 KB
#define XB_OFF 65536              // xb at 128 KiB into d_ws (in shorts)
#define NBLK 256
#define WSH (3 * IMG_SHORTS)      // 96 KB of W images (shorts)
#define RBS 4096                  // per-wave row buffer: src [0,2048), dst [2048,4096) shorts

__device__ __forceinline__ short f2bf(float f) {
    union { float f; unsigned u; } v; v.f = f;
    unsigned r = (v.u + 0x7FFFu + ((v.u >> 16) & 1u)) >> 16;  // RNE
    return (short)r;
}

__device__ __forceinline__ short f2bf_h(float f) {
    __hip_bfloat16 h = __float2bfloat16(f);
    short s;
    __builtin_memcpy(&s, &h, sizeof(short));
    return s;
}

__device__ __forceinline__ bf16x8 pack8(f32x4 a, f32x4 b) {
    bf16x8 r;
    r[0] = f2bf_h(a[0]); r[1] = f2bf_h(a[1]); r[2] = f2bf_h(a[2]); r[3] = f2bf_h(a[3]);
    r[4] = f2bf_h(b[0]); r[5] = f2bf_h(b[1]); r[6] = f2bf_h(b[2]); r[7] = f2bf_h(b[3]);
    return r;
}

__device__ __forceinline__ void gload_lds16(const short* g, short* l) {
    __builtin_amdgcn_global_load_lds(
        (const __attribute__((address_space(1))) unsigned int*)(const void*)g,
        (__attribute__((address_space(3))) unsigned int*)(void*)l, 16, 0, 0);
}

// W (3*128 x 128 fp32 row-major) -> 3 A-operand fragment images (src,dst,e):
// img[c][frag=mt*4+ks][lane][j] = W[c*128 + ks*32 + (lane>>4)*8 + j][mt*16 + (lane&15)]
__global__ __launch_bounds__(256) void wt_kernel(const float* __restrict__ W,
                                                 short* __restrict__ Wimg) {
    const int c    = blockIdx.x >> 3;
    const int frag = (blockIdx.x & 7) * 4 + (threadIdx.x >> 6);
    const int lane = threadIdx.x & 63;
    const int mt = frag >> 2, ks = frag & 3;
    const int m  = mt * 16 + (lane & 15);
    const int k0 = ks * 32 + (lane >> 4) * 8;
    bf16x8 v;
#pragma unroll
    for (int j = 0; j < 8; ++j)
        v[j] = f2bf(W[(size_t)(c * 128 + k0 + j) * D128 + m]);
    *reinterpret_cast<bf16x8*>(
        &Wimg[((size_t)c * 32 + frag) * 64 * 8 + (size_t)lane * 8]) = v;
}

// x (fp32) -> xb (bf16), 8 elems/thread.
__global__ __launch_bounds__(256) void xb_kernel(const float* __restrict__ x,
                                                 short* __restrict__ xb) {
    const size_t i = ((size_t)blockIdx.x * 256 + threadIdx.x) * 8;
    f32x4 v0 = reinterpret_cast<const f32x4*>(x + i)[0];
    f32x4 v1 = reinterpret_cast<const f32x4*>(x + i)[1];
    *reinterpret_cast<bf16x8*>(xb + i) = pack8(v0, v1);
}

// Fused kernel: R9 skeleton (persistent W images, wave-private row buffers,
// DMA gathers with cross-iteration prefetch, counted vmcnt 14->10->6, no loop
// barriers) + QUAD-COALESCED gather DMA:
//   issuing lane l: r=l>>2 (row), q=l&3 (16B quarter), sx=(r>>1)&3 XOR twist.
//   Each quad covers one contiguous 64B span of one xb row (1 segment vs 4).
//   LDS dest stays linear (lane*16B); fragment readback at
//   slot = fr*4 + (lhi^sx(fr))  => content chunk (q^sx)^sx = lhi. 2 lanes per
//   bank-quad per 16-lane group => conflict-free.
// e loads and out stores keep the (proven) R9 fragment-shaped form: they hit
// 16 CONTIGUOUS rows (full 128B lines), unlike the random-row gathers.
__global__ __launch_bounds__(512, 2) void fused_kernel(
        const short* __restrict__ xb,
        const float* __restrict__ e,
        const short* __restrict__ Wimg,
        const int*  __restrict__ src_idx,
        const int*  __restrict__ dst_idx,
        float* __restrict__ out,
        int E, int ntiles)
{
    __shared__ short lds[WSH + 8 * RBS];   // 160 KB exact

    const int tid  = threadIdx.x;
    const int lane = tid & 63;
    const int w    = tid >> 6;            // 0..7
    const int r    = lane >> 2;           // 0..15: row this lane's DMA serves
    const int q    = lane & 3;            // 16B quarter within the 64B span
    const int sx   = (r >> 1) & 3;        // XOR twist (DMA source side)
    const int fr   = lane & 15;           // frag row this lane COMPUTES
    const int lhi  = lane >> 4;           // frag k-quarter
    // gather readback slot: row fr, want chunk lhi, stored at lhi^sx(fr)
    const int rb_off = (fr * 4 + (lhi ^ ((fr >> 1) & 3))) * 8;   // shorts

    short* RB = &lds[WSH + w * RBS];

    // contiguous tile range for this block
    const int per = ntiles >> 8;
    const int rem = ntiles & 255;
    const int b   = blockIdx.x;
    const int t0  = b * per + (b < rem ? b : rem);
    const int t1  = t0 + per + (b < rem ? 1 : 0);

    // ---- prologue: stage W images (12 DMA/thread, linear both sides) ----
#pragma unroll
    for (int jj = 0; jj < 12; ++jj) {
        int unit = jj * 512 + tid;
        gload_lds16(Wimg + (size_t)unit * 8, &lds[unit * 8]);
    }
    int rp = t0 * 128 + w * 16 + r;
    int si = src_idx[rp];
    int di = dst_idx[rp];
    asm volatile("" ::: "memory");
    asm volatile("s_waitcnt vmcnt(0)" ::: "memory");
    __builtin_amdgcn_s_barrier();          // the only barrier

    // ---- DMA src[t0]: quad-coalesced source, linear LDS dest ----
#pragma unroll
    for (int ks = 0; ks < 4; ++ks)
        gload_lds16(xb + (size_t)si * D128 + ks * 32 + (q ^ sx) * 8, &RB[ks * 512]);
    asm volatile("" ::: "memory");

    for (int t = t0; t < t1; ++t) {
        const int rn = t * 128 + w * 16 + fr;   // compute/e/store row

        // ---- issue DMA dst[t] (4, quad-coalesced) ----
#pragma unroll
        for (int ks = 0; ks < 4; ++ks)
            gload_lds16(xb + (size_t)di * D128 + ks * 32 + (q ^ sx) * 8,
                        &RB[2048 + ks * 512]);
        asm volatile("" ::: "memory");

        // ---- issue e row loads (8, fragment-shaped; 16 contiguous rows) ----
        const float* pe = e + (size_t)rn * D128;
        f32x4 ev[8];
#pragma unroll
        for (int ks = 0; ks < 4; ++ks) {
            ev[2 * ks]     = reinterpret_cast<const f32x4*>(pe + ks * 32 + lhi * 8)[0];
            ev[2 * ks + 1] = reinterpret_cast<const f32x4*>(pe + ks * 32 + lhi * 8)[1];
        }
        asm volatile("" ::: "memory");

        // ---- issue idx[t+1] (2) ----
        int rpn = (t + 1) * 128 + w * 16 + r;
        if (rpn >= E) rpn = E - 1;
        const int sin_ = src_idx[rpn];
        const int din_ = dst_idx[rpn];
        asm volatile("" ::: "memory");

        // src[t] ready (retires prev src'4 + prev stores8; dst4+e8+idx2 fly)
        asm volatile("s_waitcnt vmcnt(14)" ::: "memory");
        __builtin_amdgcn_sched_barrier(0);

        f32x4 acc[8];
#pragma unroll
        for (int mt = 0; mt < 8; ++mt) acc[mt] = (f32x4){0.f, 0.f, 0.f, 0.f};

        // ---- chunk 0: src rows from RB[0,4K), twisted slot readback ----
#pragma unroll
        for (int ks = 0; ks < 4; ++ks) {
            bf16x8 bfr = *reinterpret_cast<const bf16x8*>(&RB[ks * 512 + rb_off]);
#pragma unroll
            for (int mt = 0; mt < 8; ++mt) {
                bf16x8 a = *reinterpret_cast<const bf16x8*>(
                    &lds[((0 * 32 + mt * 4 + ks) * 64 + lane) * 8]);
                acc[mt] = __builtin_amdgcn_mfma_f32_16x16x32_bf16(a, bfr, acc[mt], 0, 0, 0);
            }
        }

        // dst[t] ready (e8+idx2 fly)
        asm volatile("s_waitcnt vmcnt(10)" ::: "memory");
        __builtin_amdgcn_sched_barrier(0);

        // ---- chunk 1: dst rows from RB[4K,8K) ----
#pragma unroll
        for (int ks = 0; ks < 4; ++ks) {
            bf16x8 bfr = *reinterpret_cast<const bf16x8*>(&RB[2048 + ks * 512 + rb_off]);
#pragma unroll
            for (int mt = 0; mt < 8; ++mt) {
                bf16x8 a = *reinterpret_cast<const bf16x8*>(
                    &lds[((1 * 32 + mt * 4 + ks) * 64 + lane) * 8]);
                acc[mt] = __builtin_amdgcn_mfma_f32_16x16x32_bf16(a, bfr, acc[mt], 0, 0, 0);
            }
        }
        asm volatile("" ::: "memory");

        // ---- issue DMA src[t+1] (4) into src buf (chunk-0 reads done) ----
#pragma unroll
        for (int ks = 0; ks < 4; ++ks)
            gload_lds16(xb + (size_t)sin_ * D128 + ks * 32 + (q ^ sx) * 8, &RB[ks * 512]);
        asm volatile("" ::: "memory");
        si = sin_; di = din_;

        // e ready (idx2 + src'4 fly)
        asm volatile("s_waitcnt vmcnt(6)" ::: "memory");
        __builtin_amdgcn_sched_barrier(0);

        // ---- chunk 2: e (pack then MFMA) ----
        bf16x8 be[4];
#pragma unroll
        for (int ks = 0; ks < 4; ++ks) be[ks] = pack8(ev[2 * ks], ev[2 * ks + 1]);
#pragma unroll
        for (int ks = 0; ks < 4; ++ks)
#pragma unroll
            for (int mt = 0; mt < 8; ++mt) {
                bf16x8 a = *reinterpret_cast<const bf16x8*>(
                    &lds[((2 * 32 + mt * 4 + ks) * 64 + lane) * 8]);
                acc[mt] = __builtin_amdgcn_mfma_f32_16x16x32_bf16(a, be[ks], acc[mt], 0, 0, 0);
            }

        // ---- epilogue: lane owns out[rn][mt*16 + lhi*4 .. +3] ----
        float* po = out + (size_t)rn * D128 + lhi * 4;
#pragma unroll
        for (int mt = 0; mt < 8; ++mt)
            *reinterpret_cast<f32x4*>(po + mt * 16) = acc[mt];
        asm volatile("" ::: "memory");   // stores precede next iter's issues
    }
}

extern "C" void kernel_launch(void* const* d_in, const int* in_sizes, int n_in,
                              void* d_out, int out_size, void* d_ws, size_t ws_size,
                              hipStream_t stream) {
    const float* x = (const float*)d_in[0];
    const float* e = (const float*)d_in[1];
    const float* W = (const float*)d_in[2];
    const int* src = (const int*)d_in[3];
    const int* dst = (const int*)d_in[4];
    float* out = (float*)d_out;

    short* Wimg = (short*)d_ws;                 // 3 x 32 KB frag images
    short* xb   = (short*)d_ws + XB_OFF;        // 100000*128 bf16 = 25.6 MB

    const int N = in_sizes[0] / D128;           // 100000
    const int E = in_sizes[3];                  // 400000
    const int ntiles = E / 128;                 // 3125 (exact)

    wt_kernel<<<24, 256, 0, stream>>>(W, Wimg);
    xb_kernel<<<(N * D128) / (256 * 8), 256, 0, stream>>>(x, xb);
    fused_kernel<<<NBLK, 512, 0, stream>>>(xb, e, Wimg, src, dst, out, E, ntiles);
}

// Round 12
// 125.736 us; speedup vs baseline: 1.2777x; 1.0299x over previous
//
#include <hip/hip_runtime.h>
#include <hip/hip_bf16.h>

typedef __attribute__((ext_vector_type(8))) short bf16x8;
typedef __attribute__((ext_vector_type(4))) float f32x4;

#define D128 128
#define IMG_SHORTS 16384          // one W frag-image: 32 frags x 64 lanes x 8 bf16 = 32 KB
#define XB_OFF 65536              // xb at 128 KiB into d_ws (in shorts)
#define NBLK 256
#define WSH (3 * IMG_SHORTS)      // 96 KB of W images (shorts)
#define RBS 4096                  // per-wave: src rows [0,2048), bounce buf [2048,4096) shorts

__device__ __forceinline__ short f2bf(float f) {
    union { float f; unsigned u; } v; v.f = f;
    unsigned r = (v.u + 0x7FFFu + ((v.u >> 16) & 1u)) >> 16;  // RNE
    return (short)r;
}

__device__ __forceinline__ short f2bf_h(float f) {
    __hip_bfloat16 h = __float2bfloat16(f);
    short s;
    __builtin_memcpy(&s, &h, sizeof(short));
    return s;
}

__device__ __forceinline__ bf16x8 pack8(f32x4 a, f32x4 b) {
    bf16x8 r;
    r[0] = f2bf_h(a[0]); r[1] = f2bf_h(a[1]); r[2] = f2bf_h(a[2]); r[3] = f2bf_h(a[3]);
    r[4] = f2bf_h(b[0]); r[5] = f2bf_h(b[1]); r[6] = f2bf_h(b[2]); r[7] = f2bf_h(b[3]);
    return r;
}

__device__ __forceinline__ void gload_lds16(const short* g, short* l) {
    __builtin_amdgcn_global_load_lds(
        (const __attribute__((address_space(1))) unsigned int*)(const void*)g,
        (__attribute__((address_space(3))) unsigned int*)(void*)l, 16, 0, 0);
}

// W (3*128 x 128 fp32 row-major) -> 3 A-operand fragment images (src,dst,e):
// img[c][frag=mt*4+ks][lane][j] = W[c*128 + ks*32 + (lane>>4)*8 + j][mt*16 + (lane&15)]
__global__ __launch_bounds__(256) void wt_kernel(const float* __restrict__ W,
                                                 short* __restrict__ Wimg) {
    const int c    = blockIdx.x >> 3;
    const int frag = (blockIdx.x & 7) * 4 + (threadIdx.x >> 6);
    const int lane = threadIdx.x & 63;
    const int mt = frag >> 2, ks = frag & 3;
    const int m  = mt * 16 + (lane & 15);
    const int k0 = ks * 32 + (lane >> 4) * 8;
    bf16x8 v;
#pragma unroll
    for (int j = 0; j < 8; ++j)
        v[j] = f2bf(W[(size_t)(c * 128 + k0 + j) * D128 + m]);
    *reinterpret_cast<bf16x8*>(
        &Wimg[((size_t)c * 32 + frag) * 64 * 8 + (size_t)lane * 8]) = v;
}

// x (fp32) -> xb (bf16), 8 elems/thread.
__global__ __launch_bounds__(256) void xb_kernel(const float* __restrict__ x,
                                                 short* __restrict__ xb) {
    const size_t i = ((size_t)blockIdx.x * 256 + threadIdx.x) * 8;
    f32x4 v0 = reinterpret_cast<const f32x4*>(x + i)[0];
    f32x4 v1 = reinterpret_cast<const f32x4*>(x + i)[1];
    *reinterpret_cast<bf16x8*>(xb + i) = pack8(v0, v1);
}

// Fused kernel, all global streams quad-coalesced:
//  - gathers: quad-coalesced DMA (R11, verified), readback slot lhi^sx(fr)
//  - e: quad loads into regs, 2x 4KB LDS bounce rounds (twist tw(r)) to
//    fragment order, pack, MFMA
//  - stores: plane bounce through same buf -> 8 quad-coalesced 64B stores
// Bounce buffer = dst row region [2048,4096): DMA dst[t] -> chunk1 reads ->
// e rounds -> store rounds; per-wave in-order DS pipe makes this safe.
__global__ __launch_bounds__(512, 2) void fused_kernel(
        const short* __restrict__ xb,
        const float* __restrict__ e,
        const short* __restrict__ Wimg,
        const int*  __restrict__ src_idx,
        const int*  __restrict__ dst_idx,
        float* __restrict__ out,
        int E, int ntiles)
{
    __shared__ short lds[WSH + 8 * RBS];   // 160 KB exact

    const int tid  = threadIdx.x;
    const int lane = tid & 63;
    const int w    = tid >> 6;            // 0..7
    const int r    = lane >> 2;           // 0..15: row this lane LOADS/STORES
    const int q    = lane & 3;            // 16B quarter within the 64B span
    const int sx   = (r >> 1) & 3;        // XOR twist (gather DMA / store-read)
    const int fr   = lane & 15;           // frag row this lane COMPUTES
    const int lhi  = lane >> 4;           // frag k-quarter / col sub
    // gather readback slot (verified R11)
    const int rb_off = (fr * 4 + (lhi ^ ((fr >> 1) & 3))) * 8;   // shorts
    // e-bounce twists: tw(n) = ((n&1)<<2) ^ ((n>>1)&3)
    const int tw_w = ((r  & 1) << 2) ^ ((r  >> 1) & 3);   // write side (lane r,q)
    const int tw_r = ((fr & 1) << 2) ^ ((fr >> 1) & 3);   // read side (lane fr,lhi)
    // store-bounce offsets
    const int st_w = (fr * 4 + (lhi ^ ((fr >> 1) & 3))) * 8;   // write (frag order)
    const int st_r = (r  * 4 + (q   ^ sx)) * 8;                // read  (store order)

    short* RB = &lds[WSH + w * RBS];
    short* BB = RB + 2048;                // 4 KB bounce / dst-row buffer

    // contiguous tile range for this block
    const int per = ntiles >> 8;
    const int rem = ntiles & 255;
    const int b   = blockIdx.x;
    const int t0  = b * per + (b < rem ? b : rem);
    const int t1  = t0 + per + (b < rem ? 1 : 0);

    // ---- prologue: stage W images (12 DMA/thread, linear both sides) ----
#pragma unroll
    for (int jj = 0; jj < 12; ++jj) {
        int unit = jj * 512 + tid;
        gload_lds16(Wimg + (size_t)unit * 8, &lds[unit * 8]);
    }
    int rp = t0 * 128 + w * 16 + r;
    int si = src_idx[rp];
    int di = dst_idx[rp];
    asm volatile("" ::: "memory");
    asm volatile("s_waitcnt vmcnt(0)" ::: "memory");
    __builtin_amdgcn_s_barrier();          // the only barrier

    // ---- DMA src[t0]: quad-coalesced source, linear LDS dest ----
#pragma unroll
    for (int ks = 0; ks < 4; ++ks)
        gload_lds16(xb + (size_t)si * D128 + ks * 32 + (q ^ sx) * 8, &RB[ks * 512]);
    asm volatile("" ::: "memory");

    for (int t = t0; t < t1; ++t) {
        const int lrow = t * 128 + w * 16 + r;    // row this lane loads/stores

        // ---- issue DMA dst[t] (4, quad-coalesced) into BB ----
#pragma unroll
        for (int ks = 0; ks < 4; ++ks)
            gload_lds16(xb + (size_t)di * D128 + ks * 32 + (q ^ sx) * 8,
                        &BB[ks * 512]);
        asm volatile("" ::: "memory");

        // ---- issue e loads (8, quad-coalesced 64B spans) ----
        const float* pe = e + (size_t)lrow * D128;
        f32x4 ev[8];
#pragma unroll
        for (int j = 0; j < 8; ++j)
            ev[j] = *reinterpret_cast<const f32x4*>(pe + (q + 4 * j) * 4);
        asm volatile("" ::: "memory");

        // ---- issue idx[t+1] (2) ----
        int rpn = (t + 1) * 128 + w * 16 + r;
        if (rpn >= E) rpn = E - 1;
        const int sin_ = src_idx[rpn];
        const int din_ = dst_idx[rpn];
        asm volatile("" ::: "memory");

        // src[t] ready (retires prev src'4 + prev stores8; dst4+e8+idx2 fly)
        asm volatile("s_waitcnt vmcnt(14)" ::: "memory");
        __builtin_amdgcn_sched_barrier(0);

        f32x4 acc[8];
#pragma unroll
        for (int mt = 0; mt < 8; ++mt) acc[mt] = (f32x4){0.f, 0.f, 0.f, 0.f};

        // ---- chunk 0: src rows from RB, twisted slot readback ----
#pragma unroll
        for (int ks = 0; ks < 4; ++ks) {
            bf16x8 bfr = *reinterpret_cast<const bf16x8*>(&RB[ks * 512 + rb_off]);
#pragma unroll
            for (int mt = 0; mt < 8; ++mt) {
                bf16x8 a = *reinterpret_cast<const bf16x8*>(
                    &lds[((0 * 32 + mt * 4 + ks) * 64 + lane) * 8]);
                acc[mt] = __builtin_amdgcn_mfma_f32_16x16x32_bf16(a, bfr, acc[mt], 0, 0, 0);
            }
        }

        // dst[t] ready (e8+idx2 fly)
        asm volatile("s_waitcnt vmcnt(10)" ::: "memory");
        __builtin_amdgcn_sched_barrier(0);

        // ---- chunk 1: dst rows from BB ----
#pragma unroll
        for (int ks = 0; ks < 4; ++ks) {
            bf16x8 bfr = *reinterpret_cast<const bf16x8*>(&BB[ks * 512 + rb_off]);
#pragma unroll
            for (int mt = 0; mt < 8; ++mt) {
                bf16x8 a = *reinterpret_cast<const bf16x8*>(
                    &lds[((1 * 32 + mt * 4 + ks) * 64 + lane) * 8]);
                acc[mt] = __builtin_amdgcn_mfma_f32_16x16x32_bf16(a, bfr, acc[mt], 0, 0, 0);
            }
        }
        asm volatile("" ::: "memory");

        // ---- issue DMA src[t+1] (4) into RB (chunk-0 reads done) ----
#pragma unroll
        for (int ks = 0; ks < 4; ++ks)
            gload_lds16(xb + (size_t)sin_ * D128 + ks * 32 + (q ^ sx) * 8, &RB[ks * 512]);
        asm volatile("" ::: "memory");
        si = sin_; di = din_;

        // e ready (idx2 + src'4 fly)
        asm volatile("s_waitcnt vmcnt(6)" ::: "memory");
        __builtin_amdgcn_sched_barrier(0);

        // ---- chunk 2: e via 2 bounce rounds (BB free after chunk 1) ----
#pragma unroll
        for (int R = 0; R < 2; ++R) {
            // write: lane (r,q) holds ev[R*4+j'] = row-unit q+4j'(+16R)
#pragma unroll
            for (int jp = 0; jp < 4; ++jp) {
                int slot = (q + 4 * jp) ^ tw_w;
                *reinterpret_cast<f32x4*>(&BB[r * 128 + slot * 8]) = ev[R * 4 + jp];
            }
            // read in frag order, pack, MFMA (ks = R*2 + ksl)
#pragma unroll
            for (int ksl = 0; ksl < 2; ++ksl) {
                const int ks = R * 2 + ksl;
                const int u0 = ksl * 8 + lhi * 2;
                f32x4 va = *reinterpret_cast<const f32x4*>(&BB[fr * 128 + (u0 ^ tw_r) * 8]);
                f32x4 vb = *reinterpret_cast<const f32x4*>(&BB[fr * 128 + ((u0 + 1) ^ tw_r) * 8]);
                bf16x8 be = pack8(va, vb);
#pragma unroll
                for (int mt = 0; mt < 8; ++mt) {
                    bf16x8 a = *reinterpret_cast<const bf16x8*>(
                        &lds[((2 * 32 + mt * 4 + ks) * 64 + lane) * 8]);
                    acc[mt] = __builtin_amdgcn_mfma_f32_16x16x32_bf16(a, be, acc[mt], 0, 0, 0);
                }
            }
        }

        // ---- epilogue: store bounce -> quad-coalesced 64B stores ----
        float* po = out + (size_t)lrow * D128 + q * 4;
#pragma unroll
        for (int R = 0; R < 2; ++R) {
#pragma unroll
            for (int p = 0; p < 4; ++p)
                *reinterpret_cast<f32x4*>(&BB[p * 512 + st_w]) = acc[R * 4 + p];
            asm volatile("" ::: "memory");
#pragma unroll
            for (int p = 0; p < 4; ++p) {
                f32x4 v = *reinterpret_cast<const f32x4*>(&BB[p * 512 + st_r]);
                *reinterpret_cast<f32x4*>(po + (R * 4 + p) * 16) = v;
            }
            asm volatile("" ::: "memory");
        }
    }
}

extern "C" void kernel_launch(void* const* d_in, const int* in_sizes, int n_in,
                              void* d_out, int out_size, void* d_ws, size_t ws_size,
                              hipStream_t stream) {
    const float* x = (const float*)d_in[0];
    const float* e = (const float*)d_in[1];
    const float* W = (const float*)d_in[2];
    const int* src = (const int*)d_in[3];
    const int* dst = (const int*)d_in[4];
    float* out = (float*)d_out;

    short* Wimg = (short*)d_ws;                 // 3 x 32 KB frag images
    short* xb   = (short*)d_ws + XB_OFF;        // 100000*128 bf16 = 25.6 MB

    const int N = in_sizes[0] / D128;           // 100000
    const int E = in_sizes[3];                  // 400000
    const int ntiles = E / 128;                 // 3125 (exact)

    wt_kernel<<<24, 256, 0, stream>>>(W, Wimg);
    xb_kernel<<<(N * D128) / (256 * 8), 256, 0, stream>>>(x, xb);
    fused_kernel<<<NBLK, 512, 0, stream>>>(xb, e, Wimg, src, dst, out, E, ntiles);
}

// Round 13
// 125.697 us; speedup vs baseline: 1.2781x; 1.0003x over previous
//
#include <hip/hip_runtime.h>
#include <hip/hip_bf16.h>

typedef __attribute__((ext_vector_type(8))) short bf16x8;
typedef __attribute__((ext_vector_type(4))) float f32x4;

#define D128 128
#define IMG_SHORTS 16384          // one W frag-image: 32 frags x 64 lanes x 8 bf16 = 32 KB
#define XB_OFF 65536              // xb at 128 KiB into d_ws (in shorts)
#define NBLK 256
#define WSH (3 * IMG_SHORTS)      // 96 KB of W images (shorts)
#define RBS 4096                  // per-wave: src rows [0,2048), bounce buf [2048,4096) shorts

__device__ __forceinline__ short f2bf(float f) {
    union { float f; unsigned u; } v; v.f = f;
    unsigned r = (v.u + 0x7FFFu + ((v.u >> 16) & 1u)) >> 16;  // RNE
    return (short)r;
}

__device__ __forceinline__ short f2bf_h(float f) {
    __hip_bfloat16 h = __float2bfloat16(f);
    short s;
    __builtin_memcpy(&s, &h, sizeof(short));
    return s;
}

__device__ __forceinline__ bf16x8 pack8(f32x4 a, f32x4 b) {
    bf16x8 r;
    r[0] = f2bf_h(a[0]); r[1] = f2bf_h(a[1]); r[2] = f2bf_h(a[2]); r[3] = f2bf_h(a[3]);
    r[4] = f2bf_h(b[0]); r[5] = f2bf_h(b[1]); r[6] = f2bf_h(b[2]); r[7] = f2bf_h(b[3]);
    return r;
}

__device__ __forceinline__ void gload_lds16(const short* g, short* l) {
    __builtin_amdgcn_global_load_lds(
        (const __attribute__((address_space(1))) unsigned int*)(const void*)g,
        (__attribute__((address_space(3))) unsigned int*)(void*)l, 16, 0, 0);
}

// W (3*128 x 128 fp32 row-major) -> 3 A-operand fragment images (src,dst,e):
// img[c][frag=mt*4+ks][lane][j] = W[c*128 + ks*32 + (lane>>4)*8 + j][mt*16 + (lane&15)]
__global__ __launch_bounds__(256) void wt_kernel(const float* __restrict__ W,
                                                 short* __restrict__ Wimg) {
    const int c    = blockIdx.x >> 3;
    const int frag = (blockIdx.x & 7) * 4 + (threadIdx.x >> 6);
    const int lane = threadIdx.x & 63;
    const int mt = frag >> 2, ks = frag & 3;
    const int m  = mt * 16 + (lane & 15);
    const int k0 = ks * 32 + (lane >> 4) * 8;
    bf16x8 v;
#pragma unroll
    for (int j = 0; j < 8; ++j)
        v[j] = f2bf(W[(size_t)(c * 128 + k0 + j) * D128 + m]);
    *reinterpret_cast<bf16x8*>(
        &Wimg[((size_t)c * 32 + frag) * 64 * 8 + (size_t)lane * 8]) = v;
}

// x (fp32) -> xb (bf16), 8 elems/thread.
__global__ __launch_bounds__(256) void xb_kernel(const float* __restrict__ x,
                                                 short* __restrict__ xb) {
    const size_t i = ((size_t)blockIdx.x * 256 + threadIdx.x) * 8;
    f32x4 v0 = reinterpret_cast<const f32x4*>(x + i)[0];
    f32x4 v1 = reinterpret_cast<const f32x4*>(x + i)[1];
    *reinterpret_cast<bf16x8*>(xb + i) = pack8(v0, v1);
}

// Fused kernel, all global streams quad-coalesced:
//  - gathers: quad-coalesced DMA (R11, verified), readback slot lhi^sx(fr)
//  - e: quad loads into regs, 2x 4KB LDS bounce rounds (twist tw(r)) to
//    fragment order, pack, MFMA
//  - stores: plane bounce through same buf -> 8 quad-coalesced 64B stores
// Bounce buffer = dst row region [2048,4096): DMA dst[t] -> chunk1 reads ->
// e rounds -> store rounds; per-wave in-order DS pipe makes this safe.
__global__ __launch_bounds__(512, 2) void fused_kernel(
        const short* __restrict__ xb,
        const float* __restrict__ e,
        const short* __restrict__ Wimg,
        const int*  __restrict__ src_idx,
        const int*  __restrict__ dst_idx,
        float* __restrict__ out,
        int E, int ntiles)
{
    __shared__ short lds[WSH + 8 * RBS];   // 160 KB exact

    const int tid  = threadIdx.x;
    const int lane = tid & 63;
    const int w    = tid >> 6;            // 0..7
    const int r    = lane >> 2;           // 0..15: row this lane LOADS/STORES
    const int q    = lane & 3;            // 16B quarter within the 64B span
    const int sx   = (r >> 1) & 3;        // XOR twist (gather DMA / store-read)
    const int fr   = lane & 15;           // frag row this lane COMPUTES
    const int lhi  = lane >> 4;           // frag k-quarter / col sub
    // gather readback slot (verified R11)
    const int rb_off = (fr * 4 + (lhi ^ ((fr >> 1) & 3))) * 8;   // shorts
    // e-bounce twists: tw(n) = ((n&1)<<2) ^ ((n>>1)&3)
    const int tw_w = ((r  & 1) << 2) ^ ((r  >> 1) & 3);   // write side (lane r,q)
    const int tw_r = ((fr & 1) << 2) ^ ((fr >> 1) & 3);   // read side (lane fr,lhi)
    // store-bounce offsets
    const int st_w = (fr * 4 + (lhi ^ ((fr >> 1) & 3))) * 8;   // write (frag order)
    const int st_r = (r  * 4 + (q   ^ sx)) * 8;                // read  (store order)

    short* RB = &lds[WSH + w * RBS];
    short* BB = RB + 2048;                // 4 KB bounce / dst-row buffer

    // contiguous tile range for this block
    const int per = ntiles >> 8;
    const int rem = ntiles & 255;
    const int b   = blockIdx.x;
    const int t0  = b * per + (b < rem ? b : rem);
    const int t1  = t0 + per + (b < rem ? 1 : 0);

    // ---- prologue: stage W images (12 DMA/thread, linear both sides) ----
#pragma unroll
    for (int jj = 0; jj < 12; ++jj) {
        int unit = jj * 512 + tid;
        gload_lds16(Wimg + (size_t)unit * 8, &lds[unit * 8]);
    }
    int rp = t0 * 128 + w * 16 + r;
    int si = src_idx[rp];
    int di = dst_idx[rp];
    asm volatile("" ::: "memory");
    asm volatile("s_waitcnt vmcnt(0)" ::: "memory");
    __builtin_amdgcn_s_barrier();          // the only barrier

    // ---- DMA src[t0]: quad-coalesced source, linear LDS dest ----
#pragma unroll
    for (int ks = 0; ks < 4; ++ks)
        gload_lds16(xb + (size_t)si * D128 + ks * 32 + (q ^ sx) * 8, &RB[ks * 512]);
    asm volatile("" ::: "memory");

    for (int t = t0; t < t1; ++t) {
        const int lrow = t * 128 + w * 16 + r;    // row this lane loads/stores

        // ---- issue DMA dst[t] (4, quad-coalesced) into BB ----
#pragma unroll
        for (int ks = 0; ks < 4; ++ks)
            gload_lds16(xb + (size_t)di * D128 + ks * 32 + (q ^ sx) * 8,
                        &BB[ks * 512]);
        asm volatile("" ::: "memory");

        // ---- issue e loads (8, quad-coalesced 64B spans) ----
        const float* pe = e + (size_t)lrow * D128;
        f32x4 ev[8];
#pragma unroll
        for (int j = 0; j < 8; ++j)
            ev[j] = *reinterpret_cast<const f32x4*>(pe + (q + 4 * j) * 4);
        asm volatile("" ::: "memory");

        // ---- issue idx[t+1] (2) ----
        int rpn = (t + 1) * 128 + w * 16 + r;
        if (rpn >= E) rpn = E - 1;
        const int sin_ = src_idx[rpn];
        const int din_ = dst_idx[rpn];
        asm volatile("" ::: "memory");

        // src[t] ready (retires prev src'4 + prev stores8; dst4+e8+idx2 fly)
        asm volatile("s_waitcnt vmcnt(14)" ::: "memory");
        __builtin_amdgcn_sched_barrier(0);

        f32x4 acc[8];
#pragma unroll
        for (int mt = 0; mt < 8; ++mt) acc[mt] = (f32x4){0.f, 0.f, 0.f, 0.f};

        // ---- chunk 0: src rows from RB, twisted slot readback ----
#pragma unroll
        for (int ks = 0; ks < 4; ++ks) {
            bf16x8 bfr = *reinterpret_cast<const bf16x8*>(&RB[ks * 512 + rb_off]);
#pragma unroll
            for (int mt = 0; mt < 8; ++mt) {
                bf16x8 a = *reinterpret_cast<const bf16x8*>(
                    &lds[((0 * 32 + mt * 4 + ks) * 64 + lane) * 8]);
                acc[mt] = __builtin_amdgcn_mfma_f32_16x16x32_bf16(a, bfr, acc[mt], 0, 0, 0);
            }
        }

        // dst[t] ready (e8+idx2 fly)
        asm volatile("s_waitcnt vmcnt(10)" ::: "memory");
        __builtin_amdgcn_sched_barrier(0);

        // ---- chunk 1: dst rows from BB ----
#pragma unroll
        for (int ks = 0; ks < 4; ++ks) {
            bf16x8 bfr = *reinterpret_cast<const bf16x8*>(&BB[ks * 512 + rb_off]);
#pragma unroll
            for (int mt = 0; mt < 8; ++mt) {
                bf16x8 a = *reinterpret_cast<const bf16x8*>(
                    &lds[((1 * 32 + mt * 4 + ks) * 64 + lane) * 8]);
                acc[mt] = __builtin_amdgcn_mfma_f32_16x16x32_bf16(a, bfr, acc[mt], 0, 0, 0);
            }
        }
        asm volatile("" ::: "memory");

        // ---- issue DMA src[t+1] (4) into RB (chunk-0 reads done) ----
#pragma unroll
        for (int ks = 0; ks < 4; ++ks)
            gload_lds16(xb + (size_t)sin_ * D128 + ks * 32 + (q ^ sx) * 8, &RB[ks * 512]);
        asm volatile("" ::: "memory");
        si = sin_; di = din_;

        // e ready (idx2 + src'4 fly)
        asm volatile("s_waitcnt vmcnt(6)" ::: "memory");
        __builtin_amdgcn_sched_barrier(0);

        // ---- chunk 2: e via 2 bounce rounds (BB free after chunk 1) ----
#pragma unroll
        for (int R = 0; R < 2; ++R) {
            // write: lane (r,q) holds ev[R*4+j'] = row-unit q+4j'(+16R)
#pragma unroll
            for (int jp = 0; jp < 4; ++jp) {
                int slot = (q + 4 * jp) ^ tw_w;
                *reinterpret_cast<f32x4*>(&BB[r * 128 + slot * 8]) = ev[R * 4 + jp];
            }
            // read in frag order, pack, MFMA (ks = R*2 + ksl)
#pragma unroll
            for (int ksl = 0; ksl < 2; ++ksl) {
                const int ks = R * 2 + ksl;
                const int u0 = ksl * 8 + lhi * 2;
                f32x4 va = *reinterpret_cast<const f32x4*>(&BB[fr * 128 + (u0 ^ tw_r) * 8]);
                f32x4 vb = *reinterpret_cast<const f32x4*>(&BB[fr * 128 + ((u0 + 1) ^ tw_r) * 8]);
                bf16x8 be = pack8(va, vb);
#pragma unroll
                for (int mt = 0; mt < 8; ++mt) {
                    bf16x8 a = *reinterpret_cast<const bf16x8*>(
                        &lds[((2 * 32 + mt * 4 + ks) * 64 + lane) * 8]);
                    acc[mt] = __builtin_amdgcn_mfma_f32_16x16x32_bf16(a, be, acc[mt], 0, 0, 0);
                }
            }
        }

        // ---- epilogue: store bounce -> quad-coalesced 64B stores ----
        float* po = out + (size_t)lrow * D128 + q * 4;
#pragma unroll
        for (int R = 0; R < 2; ++R) {
#pragma unroll
            for (int p = 0; p < 4; ++p)
                *reinterpret_cast<f32x4*>(&BB[p * 512 + st_w]) = acc[R * 4 + p];
            asm volatile("" ::: "memory");
#pragma unroll
            for (int p = 0; p < 4; ++p) {
                f32x4 v = *reinterpret_cast<const f32x4*>(&BB[p * 512 + st_r]);
                *reinterpret_cast<f32x4*>(po + (R * 4 + p) * 16) = v;
            }
            asm volatile("" ::: "memory");
        }
    }
}

extern "C" void kernel_launch(void* const* d_in, const int* in_sizes, int n_in,
                              void* d_out, int out_size, void* d_ws, size_t ws_size,
                              hipStream_t stream) {
    const float* x = (const float*)d_in[0];
    const float* e = (const float*)d_in[1];
    const float* W = (const float*)d_in[2];
    const int* src = (const int*)d_in[3];
    const int* dst = (const int*)d_in[4];
    float* out = (float*)d_out;

    short* Wimg = (short*)d_ws;                 // 3 x 32 KB frag images
    short* xb   = (short*)d_ws + XB_OFF;        // 100000*128 bf16 = 25.6 MB

    const int N = in_sizes[0] / D128;           // 100000
    const int E = in_sizes[3];                  // 400000
    const int ntiles = E / 128;                 // 3125 (exact)

    wt_kernel<<<24, 256, 0, stream>>>(W, Wimg);
    xb_kernel<<<(N * D128) / (256 * 8), 256, 0, stream>>>(x, xb);
    fused_kernel<<<NBLK, 512, 0, stream>>>(xb, e, Wimg, src, dst, out, E, ntiles);
}